// Round 16
// baseline (18189.632 us; speedup 1.0000x reference)
//
#include <hip/hip_runtime.h>
#include <stdint.h>
#include <stddef.h>

#define T_STEPS 32768
#define HDIM    256
#define NTHR    256

typedef int v4i __attribute__((ext_vector_type(4)));

__device__ __forceinline__ float rcpf_(float x) {
#if defined(__has_builtin) && __has_builtin(__builtin_amdgcn_rcpf)
    return __builtin_amdgcn_rcpf(x);
#else
    return 1.0f / x;
#endif
}
// exact v_exp_f32: D = 2^S0
__device__ __forceinline__ float exp2f_(float x) {
    float r;
    asm("v_exp_f32 %0, %1" : "=v"(r) : "v"(x));
    return r;
}

// i8 MFMA 16x16x64: one wave-instr = 16 outputs x 64 k (exact i32 accum).
__device__ __forceinline__ v4i mfma8_(v4i a, v4i b, v4i c) {
#if defined(__has_builtin) && __has_builtin(__builtin_amdgcn_mfma_i32_16x16x64_i8)
    return __builtin_amdgcn_mfma_i32_16x16x64_i8(a, b, c, 0, 0, 0);
#else
    v4i d;
    asm("v_mfma_i32_16x16x64_i8 %0, %1, %2, %3"
        : "=a"(d) : "v"(a), "v"(b), "a"(c));
    return d;
#endif
}

// float DPP add via row_shr (legal on CDNA4; row_bcast15/31 are NOT).
#define DPPADD(v, CTRL) { \
    int _s = __builtin_amdgcn_update_dpp(0, __builtin_bit_cast(int, v), \
                                         CTRL, 0xf, 0xf, true); \
    v += __builtin_bit_cast(float, _s); }

// |w_hh| <= 1/16 exactly -> fixed scale: q = rint(w * 127/0.0625)
__device__ __forceinline__ uint32_t packw4_(const float4 v) {
    int a = __float2int_rn(v.x * 2032.0f);
    int b = __float2int_rn(v.y * 2032.0f);
    int c = __float2int_rn(v.z * 2032.0f);
    int d = __float2int_rn(v.w * 2032.0f);
    return (uint32_t)(a & 255) | ((uint32_t)(b & 255) << 8) |
           ((uint32_t)(c & 255) << 16) | ((uint32_t)(d & 255) << 24);
}

// R32 = R31 (17.74 champion: MFMA engine + fc tail software-pipelined into
// the mfma block) + GATE-ORDERED mfma issue with the r/z combine
// interleaved into the n-block. R31 validated the mechanism (same-BB VALU
// fills mfma issue-stall gaps, -107 cyc); its remaining ~250-cyc serial
// block was the combine waiting on ALL 48 mfmas (selects placed after the
// whole block). Integer accumulation is order-exact -> reorder gate-major:
// r-block(16), z-block(16, ring stores interleaved), n-block(16 with the
// r/z selects + sigmoids — the transcendental-heavy half of the combine —
// interleaved into its stall gaps). After the last n-mfma only the short
// n-chain remains (~10 dep ops ~80 cyc vs ~200). Float ops unchanged ->
// absmax must stay exactly 0.0009765625.
__global__ __launch_bounds__(NTHR)
void aether_gru_kernel(const float* __restrict__ xg,
                       const float* __restrict__ wih,
                       const float* __restrict__ whh,
                       const float* __restrict__ bih,
                       const float* __restrict__ bhh,
                       const float* __restrict__ wfc,
                       const float* __restrict__ bfc,
                       float* __restrict__ out,
                       float* __restrict__ pws_g) {
    const int tid  = threadIdx.x;
    const int lane = tid & 63;
    const int ri   = tid;                   // combine row 0..255 (= 64*wv+lane)
    const int rbase = (tid >> 6) << 6;      // wave row base 64w
    const int col  = lane & 15;             // chain col
    const int loff = (lane >> 4) << 4;      // k sub-offset within a k-tile

    __shared__ float xlds[T_STEPS + 2];
    __shared__ __align__(16) signed char hbuf[2][HDIM];
    __shared__ __align__(16) float pwsL[256 * 16];   // fc partial ring (16 KB)
    __shared__ float idxL[256];                      // event-index ring

    // ---- stage x into LDS (coalesced float4) ----
    {
        const float4* xs4 = (const float4*)xg;
        float4* xd4 = (float4*)xlds;
        #pragma unroll 4
        for (int i = 0; i < T_STEPS / 4 / NTHR; ++i)
            xd4[tid + NTHR * i] = xs4[tid + NTHR * i];
        if (tid == 0) { xlds[T_STEPS] = 0.0f; xlds[T_STEPS + 1] = 0.0f; }
    }

    // ---- B-fragments: 3 gates x 4 chains x 4 k-tiles = 48 v4i ----
#define LDB(NAME, g, c, kt) \
    v4i NAME; { \
        const float4* _r4 = (const float4*)(whh + \
            ((size_t)((g) * HDIM + rbase + 16 * (c) + col)) * HDIM + \
            64 * (kt) + loff); \
        NAME = (v4i){ (int)packw4_(_r4[0]), (int)packw4_(_r4[1]), \
                      (int)packw4_(_r4[2]), (int)packw4_(_r4[3]) }; }
    LDB(Br00,0,0,0) LDB(Br01,0,0,1) LDB(Br02,0,0,2) LDB(Br03,0,0,3)
    LDB(Br10,0,1,0) LDB(Br11,0,1,1) LDB(Br12,0,1,2) LDB(Br13,0,1,3)
    LDB(Br20,0,2,0) LDB(Br21,0,2,1) LDB(Br22,0,2,2) LDB(Br23,0,2,3)
    LDB(Br30,0,3,0) LDB(Br31,0,3,1) LDB(Br32,0,3,2) LDB(Br33,0,3,3)
    LDB(Bz00,1,0,0) LDB(Bz01,1,0,1) LDB(Bz02,1,0,2) LDB(Bz03,1,0,3)
    LDB(Bz10,1,1,0) LDB(Bz11,1,1,1) LDB(Bz12,1,1,2) LDB(Bz13,1,1,3)
    LDB(Bz20,1,2,0) LDB(Bz21,1,2,1) LDB(Bz22,1,2,2) LDB(Bz23,1,2,3)
    LDB(Bz30,1,3,0) LDB(Bz31,1,3,1) LDB(Bz32,1,3,2) LDB(Bz33,1,3,3)
    LDB(Bn00,2,0,0) LDB(Bn01,2,0,1) LDB(Bn02,2,0,2) LDB(Bn03,2,0,3)
    LDB(Bn10,2,1,0) LDB(Bn11,2,1,1) LDB(Bn12,2,1,2) LDB(Bn13,2,1,3)
    LDB(Bn20,2,2,0) LDB(Bn21,2,2,1) LDB(Bn22,2,2,2) LDB(Bn23,2,2,3)
    LDB(Bn30,2,3,0) LDB(Bn31,2,3,1) LDB(Bn32,2,3,2) LDB(Bn33,2,3,3)

    const v4i zero4 = {0, 0, 0, 0};

    // ---- per-row scalars (row = ri), exp2 (log2) domain — as R31 ----
    const float L1  = 1.4426950408889634f;           // log2(e)
    const float WSCALE = 0.0625f / 16129.0f;
    const float WSL  = WSCALE * L1;
    const float WSL2 = WSCALE * (2.0f * L1);
    const float wxr = wih[2 * ri] * L1,              wdr = wih[2 * ri + 1] * L1;
    const float wxz = wih[2 * (HDIM + ri)] * L1,     wdz = wih[2 * (HDIM + ri) + 1] * L1;
    const float wxn = wih[2 * (2*HDIM + ri)] * (2.0f*L1),
                wdn = wih[2 * (2*HDIM + ri) + 1] * (2.0f*L1);
    const float brc = (bih[ri] + bhh[ri]) * L1;
    const float bzc = (bih[HDIM + ri] + bhh[HDIM + ri]) * L1;
    const float bn2 = bih[2*HDIM + ri] * (2.0f*L1);
    const float cn2 = bhh[2*HDIM + ri] * (2.0f*L1);
    const float wf  = wfc[ri];
    const float bf  = bfc[0];

    if (tid < 64) ((float*)&hbuf[0][0])[tid] = 0.0f;   // zero h0
    __syncthreads();

    // ---- sequential state (uniform across threads -> uniform branches) ----
    float hprev    = 0.0f;
    float last_val = xlds[0] + 1.24f;       // xs[0] + (2*THRESHOLD + 1.0)
    float last_t   = 0.0f;
    int   cnt      = 0;
    int   cur      = 0;

    // pipelined fc-tail state (event e's tail runs during event e+1)
    float pend_pv = 0.0f, pend_tf = 0.0f;
    int   pend_e  = 0;

    float xc = xlds[0];
    float xn = xlds[1];

    float* recon = out;
    float* idxp  = out + T_STEPS + 1;

    // prime A-fragments (h broadcast): lane l reads h[64*kt + loff .. +15]
    const char* hbp = (const char*)&hbuf[0][0];
    v4i A0 = *(const v4i*)(hbp +   0 + loff);
    v4i A1 = *(const v4i*)(hbp +  64 + loff);
    v4i A2 = *(const v4i*)(hbp + 128 + loff);
    v4i A3 = *(const v4i*)(hbp + 192 + loff);

    for (int t = 0; t < T_STEPS; ++t) {
        float xf = xlds[t + 2];                      // LDS prefetch, 2 ahead
        const float tf = (float)t;
        const bool ev = fabsf(xc - last_val) >= 0.12f;   // uniform

        if (ev) {
            const float dtv  = (tf - last_t) * 0.01f;
            const float gir  = fmaf(wxr, xc, fmaf(wdr, dtv, brc));
            const float giz  = fmaf(wxz, xc, fmaf(wdz, dtv, bzc));
            const float gin2 = fmaf(wxn, xc, fmaf(wdn, dtv, bn2));

            float tpv = pend_pv;             // previous event's fc partial
            const int pslot = pend_e & 255;
            const bool c16 = (lane & 16) != 0;
            const bool c32 = (lane & 32) != 0;

            // ---- r-block: 16 mfma (4 chains), prev-event DPP tail in
            //      the issue-stall gaps (R31 mechanism) ----
            v4i aR0 = mfma8_(A0, Br00, zero4);
            v4i aR1 = mfma8_(A0, Br10, zero4);
            v4i aR2 = mfma8_(A0, Br20, zero4);
            DPPADD(tpv, 0x111)   // row_shr:1
            v4i aR3 = mfma8_(A0, Br30, zero4);
            aR0 = mfma8_(A1, Br01, aR0);
            aR1 = mfma8_(A1, Br11, aR1);
            DPPADD(tpv, 0x112)   // row_shr:2
            aR2 = mfma8_(A1, Br21, aR2);
            aR3 = mfma8_(A1, Br31, aR3);
            aR0 = mfma8_(A2, Br02, aR0);
            DPPADD(tpv, 0x114)   // row_shr:4
            aR1 = mfma8_(A2, Br12, aR1);
            aR2 = mfma8_(A2, Br22, aR2);
            aR3 = mfma8_(A2, Br32, aR3);
            DPPADD(tpv, 0x118)   // row_shr:8 -> lane15 of row16 = sum
            aR0 = mfma8_(A3, Br03, aR0);
            aR1 = mfma8_(A3, Br13, aR1);
            aR2 = mfma8_(A3, Br23, aR2);
            aR3 = mfma8_(A3, Br33, aR3);

            // ---- z-block: 16 mfma, ring/idx stores in the gaps ----
            v4i aZ0 = mfma8_(A0, Bz00, zero4);
            v4i aZ1 = mfma8_(A0, Bz10, zero4);
            if ((lane & 15) == 15) pwsL[(pslot << 4) | (tid >> 4)] = tpv;
            v4i aZ2 = mfma8_(A0, Bz20, zero4);
            v4i aZ3 = mfma8_(A0, Bz30, zero4);
            if (tid == 0) idxL[pslot] = pend_tf;
            aZ0 = mfma8_(A1, Bz01, aZ0);
            aZ1 = mfma8_(A1, Bz11, aZ1);
            aZ2 = mfma8_(A1, Bz21, aZ2);
            aZ3 = mfma8_(A1, Bz31, aZ3);
            aZ0 = mfma8_(A2, Bz02, aZ0);
            aZ1 = mfma8_(A2, Bz12, aZ1);
            aZ2 = mfma8_(A2, Bz22, aZ2);
            aZ3 = mfma8_(A2, Bz32, aZ3);
            aZ0 = mfma8_(A3, Bz03, aZ0);
            aZ1 = mfma8_(A3, Bz13, aZ1);
            aZ2 = mfma8_(A3, Bz23, aZ2);
            aZ3 = mfma8_(A3, Bz33, aZ3);

            // ---- n-block: 16 mfma with the r/z selects + sigmoids
            //      (transcendental half of the combine) in the gaps ----
            v4i aN0 = mfma8_(A0, Bn00, zero4);
            v4i aN1 = mfma8_(A0, Bn10, zero4);
            const int sr = c32 ? (c16 ? aR3[0] : aR2[0])
                               : (c16 ? aR1[0] : aR0[0]);
            v4i aN2 = mfma8_(A0, Bn20, zero4);
            v4i aN3 = mfma8_(A0, Bn30, zero4);
            const float prer = fmaf((float)sr, WSL, gir);
            aN0 = mfma8_(A1, Bn01, aN0);
            aN1 = mfma8_(A1, Bn11, aN1);
            const int sz = c32 ? (c16 ? aZ3[0] : aZ2[0])
                               : (c16 ? aZ1[0] : aZ0[0]);
            aN2 = mfma8_(A1, Bn21, aN2);
            aN3 = mfma8_(A1, Bn31, aN3);
            const float prez = fmaf((float)sz, WSL, giz);
            aN0 = mfma8_(A2, Bn02, aN0);
            const float r  = rcpf_(1.0f + exp2f_(-prer));
            aN1 = mfma8_(A2, Bn12, aN1);
            aN2 = mfma8_(A2, Bn22, aN2);
            const float zz = rcpf_(1.0f + exp2f_(-prez));
            aN3 = mfma8_(A2, Bn32, aN3);
            aN0 = mfma8_(A3, Bn03, aN0);
            aN1 = mfma8_(A3, Bn13, aN1);
            aN2 = mfma8_(A3, Bn23, aN2);
            aN3 = mfma8_(A3, Bn33, aN3);

            // ---- short n-chain (the only post-mfma serial part) ----
            const int sn = c32 ? (c16 ? aN3[0] : aN2[0])
                               : (c16 ? aN1[0] : aN0[0]);
            const float hn2  = fmaf((float)sn, WSL2, cn2);
            const float e2 = exp2f_(fmaf(r, hn2, gin2));
            const float n  = fmaf(-2.0f, rcpf_(e2 + 1.0f), 1.0f);
            const float hnew = fmaf(zz, hprev - n, n);       // n + z(hp-n)
            hprev = hnew;

            // quantize + publish int8 h (row = ri = tid)
            hbuf[cur ^ 1][ri] = (signed char)__float2int_rn(hnew * 127.0f);

            const float mypv = hnew * wf;    // this event's fc partial
            const int   mye  = cnt;
            last_val = xc;
            last_t   = tf;
            cnt++;

            __syncthreads();                 // ONE barrier: hbuf published
            cur ^= 1;
            {   // prefetch next event's A-fragments (4 ds_read_b128)
                const char* hb2 = (const char*)&hbuf[cur][0];
                A0 = *(const v4i*)(hb2 +   0 + loff);
                A1 = *(const v4i*)(hb2 +  64 + loff);
                A2 = *(const v4i*)(hb2 + 128 + loff);
                A3 = *(const v4i*)(hb2 + 192 + loff);
            }
#if defined(__has_builtin) && __has_builtin(__builtin_amdgcn_sched_barrier)
            __builtin_amdgcn_sched_barrier(0);   // don't sink the A loads
#endif

            // ---- flush: chunk ending at pend_e fully written pre-barrier ----
            if ((pend_e & 255) == 255) {
                const int ch = pend_e >> 8;
                float4* dst = (float4*)(pws_g + ((size_t)ch << 12));
                const float4* src = (const float4*)pwsL;
                dst[tid]       = src[tid];
                dst[tid + 256] = src[tid + 256];
                dst[tid + 512] = src[tid + 512];
                dst[tid + 768] = src[tid + 768];
                idxp[(ch << 8) + tid] = idxL[tid];
                __syncthreads();             // protect ring reuse (1/256)
            }

            pend_pv = mypv; pend_e = mye; pend_tf = tf;   // rotate pipeline
        }

        xc = xn; xn = xf;
    }

    // ---- drain the pipelined tail of the last event ----
    if (cnt > 0) {
        float tpv = pend_pv;
        const int pslot = pend_e & 255;
        DPPADD(tpv, 0x111)
        DPPADD(tpv, 0x112)
        DPPADD(tpv, 0x114)
        DPPADD(tpv, 0x118)
        if ((lane & 15) == 15) pwsL[(pslot << 4) | (tid >> 4)] = tpv;
        if (tid == 0) idxL[pslot] = pend_tf;
    }
    __syncthreads();    // make last ring writes visible to the final flush

    // ---- final flush: events [fl*256, cnt) still in the ring ----
    {
        const int fl  = (cnt > 0) ? ((cnt - 1) >> 8) : 0;  // chunks flushed
        const int rem = cnt - (fl << 8);
        if (rem > 0) {
            for (int i = tid; i < (rem << 4); i += NTHR)
                pws_g[(((size_t)fl << 8) << 4) + i] = pwsL[i];
            if (tid < rem) idxp[(fl << 8) + tid] = idxL[tid];
        }
    }
    if (tid == 0) out[T_STEPS] = (float)cnt;          // n_events
    for (int i = cnt + tid; i < T_STEPS; i += NTHR)
        idxp[i] = 32768.0f;                           // pad with T
    __syncthreads();                                  // drain flush stores

    // ---- epilogue: pred per event + piecewise-constant recon fill ----
    for (int k = tid; k < cnt; k += NTHR) {
        const float4* s = (const float4*)(pws_g + ((size_t)k << 4));
        float4 a = s[0], b = s[1], c = s[2], d = s[3];
        float pred = ((a.x + a.y) + (a.z + a.w)) + ((b.x + b.y) + (b.z + b.w))
                   + ((c.x + c.y) + (c.z + c.w)) + ((d.x + d.y) + (d.z + d.w)) + bf;
        const int t0 = (int)idxp[k];
        const int t1 = (k + 1 < cnt) ? (int)idxp[k + 1] : T_STEPS;
        for (int t = t0; t < t1; ++t) recon[t] = pred;
    }
}

extern "C" void kernel_launch(void* const* d_in, const int* in_sizes, int n_in,
                              void* d_out, int out_size, void* d_ws, size_t ws_size,
                              hipStream_t stream) {
    const float* x    = (const float*)d_in[0];
    const float* wih  = (const float*)d_in[1];
    const float* whh  = (const float*)d_in[2];
    const float* bih  = (const float*)d_in[3];
    const float* bhh  = (const float*)d_in[4];
    const float* wfc  = (const float*)d_in[5];
    const float* bfc  = (const float*)d_in[6];
    float* out = (float*)d_out;
    float* pws = (float*)d_ws;   // <= 2 MB (30592 events x 64 B)

    hipLaunchKernelGGL(aether_gru_kernel, dim3(1), dim3(NTHR), 0, stream,
                       x, wih, whh, bih, bhh, wfc, bfc, out, pws);
}

// Round 17
// 17677.039 us; speedup vs baseline: 1.0290x; 1.0290x over previous
//
#include <hip/hip_runtime.h>
#include <stdint.h>
#include <stddef.h>

#define T_STEPS 32768
#define HDIM    256
#define NTHR    256

typedef int v4i __attribute__((ext_vector_type(4)));

__device__ __forceinline__ float rcpf_(float x) {
#if defined(__has_builtin) && __has_builtin(__builtin_amdgcn_rcpf)
    return __builtin_amdgcn_rcpf(x);
#else
    return 1.0f / x;
#endif
}
// exact v_exp_f32: D = 2^S0
__device__ __forceinline__ float exp2f_(float x) {
    float r;
    asm("v_exp_f32 %0, %1" : "=v"(r) : "v"(x));
    return r;
}

// i8 MFMA 16x16x64: one wave-instr = 16 outputs x 64 k (exact i32 accum).
__device__ __forceinline__ v4i mfma8_(v4i a, v4i b, v4i c) {
#if defined(__has_builtin) && __has_builtin(__builtin_amdgcn_mfma_i32_16x16x64_i8)
    return __builtin_amdgcn_mfma_i32_16x16x64_i8(a, b, c, 0, 0, 0);
#else
    v4i d;
    asm("v_mfma_i32_16x16x64_i8 %0, %1, %2, %3"
        : "=a"(d) : "v"(a), "v"(b), "a"(c));
    return d;
#endif
}

// float DPP add via row_shr (legal on CDNA4; row_bcast15/31 are NOT).
#define DPPADD(v, CTRL) { \
    int _s = __builtin_amdgcn_update_dpp(0, __builtin_bit_cast(int, v), \
                                         CTRL, 0xf, 0xf, true); \
    v += __builtin_bit_cast(float, _s); }

// |w_hh| <= 1/16 exactly -> fixed scale: q = rint(w * 127/0.0625)
__device__ __forceinline__ uint32_t packw4_(const float4 v) {
    int a = __float2int_rn(v.x * 2032.0f);
    int b = __float2int_rn(v.y * 2032.0f);
    int c = __float2int_rn(v.z * 2032.0f);
    int d = __float2int_rn(v.w * 2032.0f);
    return (uint32_t)(a & 255) | ((uint32_t)(b & 255) << 8) |
           ((uint32_t)(c & 255) << 16) | ((uint32_t)(d & 255) << 24);
}

// R33 = R31 verbatim (17.74 ms champion), reverting R32's gate-ordered
// interleave (18.19: manual placement only PERTURBED the scheduler — the
// event body is one BB, so the compiler already hoists the r/z combine
// into mfma issue gaps; hand-pinning removed freedom, +35 cyc/event).
// Structure: MFMA dot engine (48x mfma_i32_16x16x64_i8/wave, layout
// verified by exact absmax) + fc tail software-pipelined one event deep
// into the next event's mfma block (R31's -107 cyc win) + one barrier
// per event + LDS fc ring with post-barrier flush.
// Structural accounting (1387 cyc/event): 768 mfma-pipe (matvec uses
// 1/16 of each mfma — irreducible: B is shared across A rows, so k-tiles
// can't fold into A; batching impossible, recurrence is sequential) +
// ~250 dependent combine + ~150 barrier/publish (every wave reads all of
// h) + ~180 scan/misc. Overlap mechanisms tested: cross-wave lockstep
// (R27 null), forced skew (R28 null), forced intra-wave ladder (R29 bad),
// helper waves (R30: 2 waves/SIMD halves reg budget -> spill), same-BB
// pipelining (R31: WORKS, kept), manual gate-order (R32: regressed).
// absmax must stay exactly 0.0009765625.
__global__ __launch_bounds__(NTHR)
void aether_gru_kernel(const float* __restrict__ xg,
                       const float* __restrict__ wih,
                       const float* __restrict__ whh,
                       const float* __restrict__ bih,
                       const float* __restrict__ bhh,
                       const float* __restrict__ wfc,
                       const float* __restrict__ bfc,
                       float* __restrict__ out,
                       float* __restrict__ pws_g) {
    const int tid  = threadIdx.x;
    const int lane = tid & 63;
    const int ri   = tid;                   // combine row 0..255 (= 64*wv+lane)
    const int rbase = (tid >> 6) << 6;      // wave row base 64w
    const int col  = lane & 15;             // chain col
    const int loff = (lane >> 4) << 4;      // k sub-offset within a k-tile

    __shared__ float xlds[T_STEPS + 2];
    __shared__ __align__(16) signed char hbuf[2][HDIM];
    __shared__ __align__(16) float pwsL[256 * 16];   // fc partial ring (16 KB)
    __shared__ float idxL[256];                      // event-index ring

    // ---- stage x into LDS (coalesced float4) ----
    {
        const float4* xs4 = (const float4*)xg;
        float4* xd4 = (float4*)xlds;
        #pragma unroll 4
        for (int i = 0; i < T_STEPS / 4 / NTHR; ++i)
            xd4[tid + NTHR * i] = xs4[tid + NTHR * i];
        if (tid == 0) { xlds[T_STEPS] = 0.0f; xlds[T_STEPS + 1] = 0.0f; }
    }

    // ---- B-fragments: 3 gates x 4 chains x 4 k-tiles = 48 v4i ----
#define LDB(NAME, g, c, kt) \
    v4i NAME; { \
        const float4* _r4 = (const float4*)(whh + \
            ((size_t)((g) * HDIM + rbase + 16 * (c) + col)) * HDIM + \
            64 * (kt) + loff); \
        NAME = (v4i){ (int)packw4_(_r4[0]), (int)packw4_(_r4[1]), \
                      (int)packw4_(_r4[2]), (int)packw4_(_r4[3]) }; }
    LDB(Br00,0,0,0) LDB(Br01,0,0,1) LDB(Br02,0,0,2) LDB(Br03,0,0,3)
    LDB(Br10,0,1,0) LDB(Br11,0,1,1) LDB(Br12,0,1,2) LDB(Br13,0,1,3)
    LDB(Br20,0,2,0) LDB(Br21,0,2,1) LDB(Br22,0,2,2) LDB(Br23,0,2,3)
    LDB(Br30,0,3,0) LDB(Br31,0,3,1) LDB(Br32,0,3,2) LDB(Br33,0,3,3)
    LDB(Bz00,1,0,0) LDB(Bz01,1,0,1) LDB(Bz02,1,0,2) LDB(Bz03,1,0,3)
    LDB(Bz10,1,1,0) LDB(Bz11,1,1,1) LDB(Bz12,1,1,2) LDB(Bz13,1,1,3)
    LDB(Bz20,1,2,0) LDB(Bz21,1,2,1) LDB(Bz22,1,2,2) LDB(Bz23,1,2,3)
    LDB(Bz30,1,3,0) LDB(Bz31,1,3,1) LDB(Bz32,1,3,2) LDB(Bz33,1,3,3)
    LDB(Bn00,2,0,0) LDB(Bn01,2,0,1) LDB(Bn02,2,0,2) LDB(Bn03,2,0,3)
    LDB(Bn10,2,1,0) LDB(Bn11,2,1,1) LDB(Bn12,2,1,2) LDB(Bn13,2,1,3)
    LDB(Bn20,2,2,0) LDB(Bn21,2,2,1) LDB(Bn22,2,2,2) LDB(Bn23,2,2,3)
    LDB(Bn30,2,3,0) LDB(Bn31,2,3,1) LDB(Bn32,2,3,2) LDB(Bn33,2,3,3)

    const v4i zero4 = {0, 0, 0, 0};

    // ---- per-row scalars (row = ri), exp2 (log2) domain ----
    const float L1  = 1.4426950408889634f;           // log2(e)
    const float WSCALE = 0.0625f / 16129.0f;
    const float WSL  = WSCALE * L1;
    const float WSL2 = WSCALE * (2.0f * L1);
    const float wxr = wih[2 * ri] * L1,              wdr = wih[2 * ri + 1] * L1;
    const float wxz = wih[2 * (HDIM + ri)] * L1,     wdz = wih[2 * (HDIM + ri) + 1] * L1;
    const float wxn = wih[2 * (2*HDIM + ri)] * (2.0f*L1),
                wdn = wih[2 * (2*HDIM + ri) + 1] * (2.0f*L1);
    const float brc = (bih[ri] + bhh[ri]) * L1;
    const float bzc = (bih[HDIM + ri] + bhh[HDIM + ri]) * L1;
    const float bn2 = bih[2*HDIM + ri] * (2.0f*L1);
    const float cn2 = bhh[2*HDIM + ri] * (2.0f*L1);
    const float wf  = wfc[ri];
    const float bf  = bfc[0];

    if (tid < 64) ((float*)&hbuf[0][0])[tid] = 0.0f;   // zero h0
    __syncthreads();

    // ---- sequential state (uniform across threads -> uniform branches) ----
    float hprev    = 0.0f;
    float last_val = xlds[0] + 1.24f;       // xs[0] + (2*THRESHOLD + 1.0)
    float last_t   = 0.0f;
    int   cnt      = 0;
    int   cur      = 0;

    // pipelined fc-tail state (event e's tail runs during event e+1);
    // dummy init is harmless: writes slot 0, later overwritten by real
    // event 0's tail; flush keys on pend_e&255==255 (false for dummy).
    float pend_pv = 0.0f, pend_tf = 0.0f;
    int   pend_e  = 0;

    float xc = xlds[0];
    float xn = xlds[1];

    float* recon = out;
    float* idxp  = out + T_STEPS + 1;

    // prime A-fragments (h broadcast): lane l reads h[64*kt + loff .. +15]
    const char* hbp = (const char*)&hbuf[0][0];
    v4i A0 = *(const v4i*)(hbp +   0 + loff);
    v4i A1 = *(const v4i*)(hbp +  64 + loff);
    v4i A2 = *(const v4i*)(hbp + 128 + loff);
    v4i A3 = *(const v4i*)(hbp + 192 + loff);

    for (int t = 0; t < T_STEPS; ++t) {
        float xf = xlds[t + 2];                      // LDS prefetch, 2 ahead
        const float tf = (float)t;
        const bool ev = fabsf(xc - last_val) >= 0.12f;   // uniform

        if (ev) {
            const float dtv  = (tf - last_t) * 0.01f;
            const float gir  = fmaf(wxr, xc, fmaf(wdr, dtv, brc));
            const float giz  = fmaf(wxz, xc, fmaf(wdz, dtv, bzc));
            const float gin2 = fmaf(wxn, xc, fmaf(wdn, dtv, bn2));

            float tpv = pend_pv;             // previous event's fc partial
            const int pslot = pend_e & 255;

            // ---- 48 mfma (12 indep chains) with the PREVIOUS event's
            //      tail VALU in the same basic block: the scheduler can
            //      drop it into mfma issue-stall gaps (~16cyc cadence). ----
            v4i aR0 = mfma8_(A0, Br00, zero4);
            v4i aR1 = mfma8_(A0, Br10, zero4);
            v4i aR2 = mfma8_(A0, Br20, zero4);
            DPPADD(tpv, 0x111)   // row_shr:1
            v4i aR3 = mfma8_(A0, Br30, zero4);
            v4i aZ0 = mfma8_(A0, Bz00, zero4);
            v4i aZ1 = mfma8_(A0, Bz10, zero4);
            DPPADD(tpv, 0x112)   // row_shr:2
            v4i aZ2 = mfma8_(A0, Bz20, zero4);
            v4i aZ3 = mfma8_(A0, Bz30, zero4);
            v4i aN0 = mfma8_(A0, Bn00, zero4);
            DPPADD(tpv, 0x114)   // row_shr:4
            v4i aN1 = mfma8_(A0, Bn10, zero4);
            v4i aN2 = mfma8_(A0, Bn20, zero4);
            v4i aN3 = mfma8_(A0, Bn30, zero4);
            DPPADD(tpv, 0x118)   // row_shr:8 -> lane15 of row16 = sum

            aR0 = mfma8_(A1, Br01, aR0); aR1 = mfma8_(A1, Br11, aR1);
            aR2 = mfma8_(A1, Br21, aR2); aR3 = mfma8_(A1, Br31, aR3);
            if ((lane & 15) == 15) pwsL[(pslot << 4) | (tid >> 4)] = tpv;
            aZ0 = mfma8_(A1, Bz01, aZ0); aZ1 = mfma8_(A1, Bz11, aZ1);
            aZ2 = mfma8_(A1, Bz21, aZ2); aZ3 = mfma8_(A1, Bz31, aZ3);
            if (tid == 0) idxL[pslot] = pend_tf;
            aN0 = mfma8_(A1, Bn01, aN0); aN1 = mfma8_(A1, Bn11, aN1);
            aN2 = mfma8_(A1, Bn21, aN2); aN3 = mfma8_(A1, Bn31, aN3);

            aR0 = mfma8_(A2, Br02, aR0); aR1 = mfma8_(A2, Br12, aR1);
            aR2 = mfma8_(A2, Br22, aR2); aR3 = mfma8_(A2, Br32, aR3);
            aZ0 = mfma8_(A2, Bz02, aZ0); aZ1 = mfma8_(A2, Bz12, aZ1);
            aZ2 = mfma8_(A2, Bz22, aZ2); aZ3 = mfma8_(A2, Bz32, aZ3);
            aN0 = mfma8_(A2, Bn02, aN0); aN1 = mfma8_(A2, Bn12, aN1);
            aN2 = mfma8_(A2, Bn22, aN2); aN3 = mfma8_(A2, Bn32, aN3);

            aR0 = mfma8_(A3, Br03, aR0); aR1 = mfma8_(A3, Br13, aR1);
            aR2 = mfma8_(A3, Br23, aR2); aR3 = mfma8_(A3, Br33, aR3);
            aZ0 = mfma8_(A3, Bz03, aZ0); aZ1 = mfma8_(A3, Bz13, aZ1);
            aZ2 = mfma8_(A3, Bz23, aZ2); aZ3 = mfma8_(A3, Bz33, aZ3);
            aN0 = mfma8_(A3, Bn03, aN0); aN1 = mfma8_(A3, Bn13, aN1);
            aN2 = mfma8_(A3, Bn23, aN2); aN3 = mfma8_(A3, Bn33, aN3);

            // ---- per-lane preact select: chain = lane>>4, col = lane&15.
            // D rows redundant (A broadcast) -> reg 0 valid. ----
            const bool c16 = (lane & 16) != 0;
            const bool c32 = (lane & 32) != 0;
            const int sr = c32 ? (c16 ? aR3[0] : aR2[0])
                               : (c16 ? aR1[0] : aR0[0]);
            const int sz = c32 ? (c16 ? aZ3[0] : aZ2[0])
                               : (c16 ? aZ1[0] : aZ0[0]);
            const int sn = c32 ? (c16 ? aN3[0] : aN2[0])
                               : (c16 ? aN1[0] : aN0[0]);

            // ---- combine ----
            const float prer = fmaf((float)sr, WSL, gir);
            const float prez = fmaf((float)sz, WSL, giz);
            const float hn2  = fmaf((float)sn, WSL2, cn2);
            const float r  = rcpf_(1.0f + exp2f_(-prer));
            const float zz = rcpf_(1.0f + exp2f_(-prez));
            const float e2 = exp2f_(fmaf(r, hn2, gin2));
            const float n  = fmaf(-2.0f, rcpf_(e2 + 1.0f), 1.0f);
            const float hnew = fmaf(zz, hprev - n, n);       // n + z(hp-n)
            hprev = hnew;

            // quantize + publish int8 h (row = ri = tid)
            hbuf[cur ^ 1][ri] = (signed char)__float2int_rn(hnew * 127.0f);

            const float mypv = hnew * wf;    // this event's fc partial
            const int   mye  = cnt;
            last_val = xc;
            last_t   = tf;
            cnt++;

            __syncthreads();                 // ONE barrier: hbuf published
            cur ^= 1;
            {   // prefetch next event's A-fragments (4 ds_read_b128)
                const char* hb2 = (const char*)&hbuf[cur][0];
                A0 = *(const v4i*)(hb2 +   0 + loff);
                A1 = *(const v4i*)(hb2 +  64 + loff);
                A2 = *(const v4i*)(hb2 + 128 + loff);
                A3 = *(const v4i*)(hb2 + 192 + loff);
            }
#if defined(__has_builtin) && __has_builtin(__builtin_amdgcn_sched_barrier)
            __builtin_amdgcn_sched_barrier(0);   // don't sink the A loads
#endif

            // ---- flush: the chunk ending at pend_e is fully written
            //      (its last ring write happened before this barrier). ----
            if ((pend_e & 255) == 255) {
                const int ch = pend_e >> 8;
                float4* dst = (float4*)(pws_g + ((size_t)ch << 12));
                const float4* src = (const float4*)pwsL;
                dst[tid]       = src[tid];
                dst[tid + 256] = src[tid + 256];
                dst[tid + 512] = src[tid + 512];
                dst[tid + 768] = src[tid + 768];
                idxp[(ch << 8) + tid] = idxL[tid];
                __syncthreads();             // protect ring reuse (1/256)
            }

            pend_pv = mypv; pend_e = mye; pend_tf = tf;   // rotate pipeline
        }

        xc = xn; xn = xf;
    }

    // ---- drain the pipelined tail of the last event ----
    if (cnt > 0) {
        float tpv = pend_pv;
        const int pslot = pend_e & 255;
        DPPADD(tpv, 0x111)
        DPPADD(tpv, 0x112)
        DPPADD(tpv, 0x114)
        DPPADD(tpv, 0x118)
        if ((lane & 15) == 15) pwsL[(pslot << 4) | (tid >> 4)] = tpv;
        if (tid == 0) idxL[pslot] = pend_tf;
    }
    __syncthreads();    // make last ring writes visible to the final flush

    // ---- final flush: events [fl*256, cnt) still in the ring ----
    {
        const int fl  = (cnt > 0) ? ((cnt - 1) >> 8) : 0;  // chunks flushed
        const int rem = cnt - (fl << 8);
        if (rem > 0) {
            for (int i = tid; i < (rem << 4); i += NTHR)
                pws_g[(((size_t)fl << 8) << 4) + i] = pwsL[i];
            if (tid < rem) idxp[(fl << 8) + tid] = idxL[tid];
        }
    }
    if (tid == 0) out[T_STEPS] = (float)cnt;          // n_events
    for (int i = cnt + tid; i < T_STEPS; i += NTHR)
        idxp[i] = 32768.0f;                           // pad with T
    __syncthreads();                                  // drain flush stores

    // ---- epilogue: pred per event + piecewise-constant recon fill ----
    for (int k = tid; k < cnt; k += NTHR) {
        const float4* s = (const float4*)(pws_g + ((size_t)k << 4));
        float4 a = s[0], b = s[1], c = s[2], d = s[3];
        float pred = ((a.x + a.y) + (a.z + a.w)) + ((b.x + b.y) + (b.z + b.w))
                   + ((c.x + c.y) + (c.z + c.w)) + ((d.x + d.y) + (d.z + d.w)) + bf;
        const int t0 = (int)idxp[k];
        const int t1 = (k + 1 < cnt) ? (int)idxp[k + 1] : T_STEPS;
        for (int t = t0; t < t1; ++t) recon[t] = pred;
    }
}

extern "C" void kernel_launch(void* const* d_in, const int* in_sizes, int n_in,
                              void* d_out, int out_size, void* d_ws, size_t ws_size,
                              hipStream_t stream) {
    const float* x    = (const float*)d_in[0];
    const float* wih  = (const float*)d_in[1];
    const float* whh  = (const float*)d_in[2];
    const float* bih  = (const float*)d_in[3];
    const float* bhh  = (const float*)d_in[4];
    const float* wfc  = (const float*)d_in[5];
    const float* bfc  = (const float*)d_in[6];
    float* out = (float*)d_out;
    float* pws = (float*)d_ws;   // <= 2 MB (30592 events x 64 B)

    hipLaunchKernelGGL(aether_gru_kernel, dim3(1), dim3(NTHR), 0, stream,
                       x, wih, whh, bih, bhh, wfc, bfc, out, pws);
}